// Round 1
// baseline (430.590 us; speedup 1.0000x reference)
//
#include <hip/hip_runtime.h>

// Problem constants (fixed by the reference)
#define N_IMG 8
#define C_CLS 19
#define H_DIM 512
#define W_DIM 1024
#define HW (H_DIM * W_DIM)              // 524288 pixels per image
#define HW2 (HW / 2)                    // 262144 float2 groups per channel
#define TOTAL_ELEMS (N_IMG * C_CLS * HW)
#define RATIO 0.2f

#define BLOCK_THREADS 256
#define BLOCKS_X (HW2 / BLOCK_THREADS)  // 1024 blocks per image, exact cover

__device__ __forceinline__ float& f2c(float2& v, int k) {
    return reinterpret_cast<float*>(&v)[k];   // k is compile-time after unroll
}

// Pass 1: per-image per-class sum of p^2 (Q) and argmax histogram (Hist) in a
// single pass over the input. Each thread owns ONE float2 per channel
// (38 payload VGPRs vs the old float4's 76 -> no spill, higher occupancy).
// Histogram: only the 2 per-component argmax indices persist; the 19-class
// ballot runs once after the main loop and goes straight to LDS.
__global__ __launch_bounds__(BLOCK_THREADS, 6) void iw_pass1(
    const float* __restrict__ in,   // (N, C, H, W)
    float* __restrict__ Q,          // [N_IMG * C_CLS], pre-zeroed
    int* __restrict__ Hist)         // [N_IMG * C_CLS], pre-zeroed
{
    const int n = blockIdx.y;
    const float2* base2 = reinterpret_cast<const float2*>(in + (size_t)n * C_CLS * HW);
    const int i = blockIdx.x * BLOCK_THREADS + threadIdx.x;   // float2 index in plane

    // 19 independent 8B/lane loads, all in flight together
    float2 x2[C_CLS];
#pragma unroll
    for (int c = 0; c < C_CLS; ++c)
        x2[c] = base2[(size_t)c * HW2 + i];

    float q[C_CLS];
#pragma unroll
    for (int c = 0; c < C_CLS; ++c) q[c] = 0.0f;

    int am0 = 0, am1 = 0;           // per-component argmax (only persistent state)
#pragma unroll
    for (int k = 0; k < 2; ++k) {
        // argmax (first index on ties, matching jnp.argmax) + running max
        float m = f2c(x2[0], k);
        int   a = 0;
#pragma unroll
        for (int c = 1; c < C_CLS; ++c) {
            float xc = f2c(x2[c], k);
            if (xc > m) { m = xc; a = c; }
        }
        if (k == 0) am0 = a; else am1 = a;

        // softmax denom; overwrite component k in place with e^2
        float S = 0.0f;
#pragma unroll
        for (int c = 0; c < C_CLS; ++c) {
            float e = __expf(f2c(x2[c], k) - m);
            S += e;
            f2c(x2[c], k) = e * e;
        }
        const float inv = __builtin_amdgcn_rcpf(S * S);   // p_c^2 = e^2 * inv
#pragma unroll
        for (int c = 0; c < C_CLS; ++c)
            q[c] = fmaf(f2c(x2[c], k), inv, q[c]);
    }

    // wave butterfly reduction of q (64 lanes); small offsets lower to DPP
#pragma unroll
    for (int c = 0; c < C_CLS; ++c) {
        float v = q[c];
#pragma unroll
        for (int off = 32; off > 0; off >>= 1)
            v += __shfl_xor(v, off, 64);
        q[c] = v;
    }

    __shared__ float qs[4 * C_CLS];
    __shared__ int   hs[4 * C_CLS];
    const int tid  = threadIdx.x;
    const int wave = tid >> 6, lane = tid & 63;

    // histogram via wave ballot: transient counts, no VGPR accumulators
#pragma unroll
    for (int c = 0; c < C_CLS; ++c) {
        int cnt = (int)__popcll(__ballot(am0 == c))
                + (int)__popcll(__ballot(am1 == c));
        if (lane == 0) hs[wave * C_CLS + c] = cnt;
    }
    if (lane == 0) {
#pragma unroll
        for (int c = 0; c < C_CLS; ++c)
            qs[wave * C_CLS + c] = q[c];
    }
    __syncthreads();
    if (tid < C_CLS) {
        float s  = qs[tid] + qs[C_CLS + tid] + qs[2 * C_CLS + tid] + qs[3 * C_CLS + tid];
        int   hv = hs[tid] + hs[C_CLS + tid] + hs[2 * C_CLS + tid] + hs[3 * C_CLS + tid];
        atomicAdd(&Q[n * C_CLS + tid], s);
        atomicAdd(&Hist[n * C_CLS + tid], hv);
    }
}

// Pass 2: weights from histogram, dot with Q, write scalar mean loss.
__global__ __launch_bounds__(64) void iw_pass2(
    const float* __restrict__ Q,
    const int* __restrict__ Hist,
    float* __restrict__ out)
{
    const int t = threadIdx.x;
    float loss = 0.0f;
    if (t < N_IMG) {
        float h[C_CLS];
        float hsum = 0.0f;
#pragma unroll
        for (int c = 0; c < C_CLS; ++c) {
            float v = (float)Hist[t * C_CLS + c];
            v = (v == 0.0f) ? 1.0f : v;                  // hist[hist==0] = 1
            h[c] = v;
            hsum += v;                                   // sum AFTER replacement
        }
#pragma unroll
        for (int c = 0; c < C_CLS; ++c) {
            float w = powf(hsum / h[c], RATIO);
            loss = fmaf(w, Q[t * C_CLS + c], loss);
        }
    }
    // reduce the 8 per-image values (lanes 8..63 contribute 0)
    loss += __shfl_xor(loss, 1, 64);
    loss += __shfl_xor(loss, 2, 64);
    loss += __shfl_xor(loss, 4, 64);
    if (t == 0)
        out[0] = -loss / (float)TOTAL_ELEMS;
}

extern "C" void kernel_launch(void* const* d_in, const int* in_sizes, int n_in,
                              void* d_out, int out_size, void* d_ws, size_t ws_size,
                              hipStream_t stream)
{
    const float* in = (const float*)d_in[0];
    float* out = (float*)d_out;

    // workspace layout: Q (float[152]) then Hist (int[152])
    float* Q  = (float*)d_ws;
    int* Hist = (int*)((char*)d_ws + N_IMG * C_CLS * sizeof(float));

    hipMemsetAsync(d_ws, 0, N_IMG * C_CLS * (sizeof(float) + sizeof(int)), stream);

    dim3 grid(BLOCKS_X, N_IMG);
    iw_pass1<<<grid, BLOCK_THREADS, 0, stream>>>(in, Q, Hist);
    iw_pass2<<<1, 64, 0, stream>>>(Q, Hist, out);
}